// Round 7
// baseline (141.491 us; speedup 1.0000x reference)
//
#include <hip/hip_runtime.h>
#include <hip/hip_bf16.h>

#define S_LEN 2048
#define D_MODEL 1024
#define NHEAD 16
#define HDIM 64
#define BATCH 2
#define M_TOT (BATCH * S_LEN)   // 4096
#define KVB 64

typedef __attribute__((ext_vector_type(4))) float f32x4;
typedef __attribute__((ext_vector_type(4))) short s16x4;
typedef __attribute__((ext_vector_type(8))) short s16x8;

#define AS1 __attribute__((address_space(1)))
#define AS3 __attribute__((address_space(3)))

#define SC2 0.18033688011112042f  // (1/8) * log2(e)

__device__ inline short f2bf(float f) {
  unsigned u = __float_as_uint(f);
  return (short)((u + 0x7fffu + ((u >> 16) & 1u)) >> 16);
}

// HW packed f32->bf16 (RNE). No builtin on gfx950 -> inline asm (T12 recipe).
__device__ __forceinline__ unsigned cvtpk(float lo, float hi) {
  unsigned r;
  asm("v_cvt_pk_bf16_f32 %0, %1, %2" : "=v"(r) : "v"(lo), "v"(hi));
  return r;
}
__device__ __forceinline__ s16x4 pk4(float a, float b, float c, float d) {
  union { unsigned u[2]; s16x4 s; } x;
  x.u[0] = cvtpk(a, b);
  x.u[1] = cvtpk(c, d);
  return x.s;
}

__device__ __forceinline__ void gl_lds16(const short* g, short* l) {
  __builtin_amdgcn_global_load_lds((const AS1 void*)g, (AS3 void*)l, 16, 0, 0);
}

// ---------------------------------------------------------------------------
// X fp32 -> bf16 cast. grid 2048, block 256, 8 elems/thread.
// ---------------------------------------------------------------------------
__global__ __launch_bounds__(256) void xcast_k(const float* __restrict__ X,
                                               short* __restrict__ Xb) {
  const size_t i = ((size_t)blockIdx.x * 256 + threadIdx.x) * 8;
  float4 a = *(const float4*)&X[i];
  float4 b = *(const float4*)&X[i + 4];
  s16x8 p;
  p[0] = f2bf(a.x); p[1] = f2bf(a.y); p[2] = f2bf(a.z); p[3] = f2bf(a.w);
  p[4] = f2bf(b.x); p[5] = f2bf(b.y); p[6] = f2bf(b.z); p[7] = f2bf(b.w);
  *(s16x8*)&Xb[i] = p;
}

// ---------------------------------------------------------------------------
// Weight transpose + cast, all 4 weights into contiguous Wcat[z][n][k].
// Wq (z==0) pre-scaled by (1/8)*log2(e). grid (32,32,4), block (32,8)
// ---------------------------------------------------------------------------
__global__ __launch_bounds__(256) void wtrans_k(const float* __restrict__ W0,
                                                const float* __restrict__ W1,
                                                const float* __restrict__ W2,
                                                const float* __restrict__ W3,
                                                short* __restrict__ Wcat) {
  const int z = blockIdx.z;
  const float* W = z == 0 ? W0 : z == 1 ? W1 : z == 2 ? W2 : W3;
  short* Wt = Wcat + (size_t)z * D_MODEL * D_MODEL;
  const float scl = (z == 0) ? SC2 : 1.f;
  __shared__ float tile[32][33];
  const int tx = threadIdx.x, ty = threadIdx.y;
  const int n0 = blockIdx.x * 32, k0 = blockIdx.y * 32;
#pragma unroll
  for (int j = 0; j < 4; ++j)
    tile[ty + j * 8][tx] = W[(size_t)(k0 + ty + j * 8) * D_MODEL + n0 + tx];
  __syncthreads();
#pragma unroll
  for (int j = 0; j < 4; ++j)
    Wt[(size_t)(n0 + ty + j * 8) * D_MODEL + k0 + tx] =
        f2bf(tile[tx][ty + j * 8] * scl);
}

// ---------------------------------------------------------------------------
// Fused QKV projection: tile 128x192, BK=64, grid 512 (32m x 16n over
// N=3072), 2-phase double-buffered, 80KB LDS = exactly 2 blocks/CU ->
// ALL blocks resident (no dispatch tail). 4 waves (2m x 2n), wave owns
// 64x96 = 4x6 frags = 48 MFMA per BK step.
// XOR slot-swizzle staging (inverse-perm global source + swizzled ds_read).
// z = n>>10 routes output per ni-column (tile may straddle Q/K/V boundary):
// z<2 -> head-split [b,h,s,d]; z==2 -> V transposed [b,h,d,s].
// ---------------------------------------------------------------------------
__global__ __launch_bounds__(256, 2) void gemm_qkv_k(
    const short* __restrict__ Xb, const short* __restrict__ Wcat,
    const float* __restrict__ bq, const float* __restrict__ bk,
    const float* __restrict__ bv, short* __restrict__ Qb,
    short* __restrict__ Kb, short* __restrict__ Vtb) {
  __shared__ short As[2 * 128 * 64];   // 32 KB
  __shared__ short Bs[2 * 192 * 64];   // 48 KB
  const int orig = blockIdx.x;                 // 512 = 64 per XCD
  const int wg = (orig & 7) * 64 + (orig >> 3);
  const int m0 = (wg >> 4) * 128;              // n-fastest within XCD chunk
  const int n0 = (wg & 15) * 192;

  const int tid = threadIdx.x;
  const int lane = tid & 63, w = tid >> 6;
  const int wm = w >> 1, wn = w & 1;
  const int lr = lane & 15, lg = lane >> 4;
  const int lr8 = lane >> 3;
  const int sl = lane & 7;
  const int scol = ((sl ^ lr8) << 3);

  f32x4 acc[4][6] = {};

  auto stage = [&](int buf, int k0) {
#pragma unroll
    for (int j = 0; j < 4; ++j) {
      const int rb = j * 4 + w;
      const int row = rb * 8 + lr8;
      gl_lds16(&Xb[(size_t)(m0 + row) * D_MODEL + k0 + scol],
               &As[buf * 8192 + rb * 512]);
    }
#pragma unroll
    for (int j = 0; j < 6; ++j) {
      const int rb = j * 4 + w;
      const int row = rb * 8 + lr8;
      gl_lds16(&Wcat[(size_t)(n0 + row) * D_MODEL + k0 + scol],
               &Bs[buf * 12288 + rb * 512]);
    }
  };

  stage(0, 0);
  __syncthreads();

  for (int t = 0; t < D_MODEL / 64; ++t) {
    const int cur = t & 1;
    if (t + 1 < D_MODEL / 64) stage(cur ^ 1, (t + 1) * 64);
    const short* Ac = As + cur * 8192;
    const short* Bc = Bs + cur * 12288;
#pragma unroll
    for (int ks = 0; ks < 2; ++ks) {
      s16x8 af[4], bfr[6];
#pragma unroll
      for (int i = 0; i < 4; ++i) {
        const int Ra = wm * 64 + i * 16 + lr;
        af[i] = *(const s16x8*)&Ac[Ra * 64 + ((((ks << 2) | lg) ^ (Ra & 7)) << 3)];
      }
#pragma unroll
      for (int i = 0; i < 6; ++i) {
        const int Rb = wn * 96 + i * 16 + lr;
        bfr[i] = *(const s16x8*)&Bc[Rb * 64 + ((((ks << 2) | lg) ^ (Rb & 7)) << 3)];
      }
      __builtin_amdgcn_s_setprio(1);
#pragma unroll
      for (int mi = 0; mi < 4; ++mi)
#pragma unroll
        for (int ni = 0; ni < 6; ++ni)
          acc[mi][ni] = __builtin_amdgcn_mfma_f32_16x16x32_bf16(
              af[mi], bfr[ni], acc[mi][ni], 0, 0, 0);
      __builtin_amdgcn_s_setprio(0);
    }
    __syncthreads();
  }

#pragma unroll
  for (int ni = 0; ni < 6; ++ni) {
    const int n = n0 + wn * 96 + ni * 16 + lr;
    const int z = n >> 10;              // uniform within a 16-chunk
    const float bn = (z == 0 ? bq[n & 1023] * SC2
                             : (z == 1 ? bk[n & 1023] : bv[n & 1023]));
    short* Cp = z == 0 ? Qb : z == 1 ? Kb : Vtb;
    const int h = (n >> 6) & 15, d = n & 63;
#pragma unroll
    for (int mi = 0; mi < 4; ++mi) {
      const int mb = m0 + wm * 64 + mi * 16 + lg * 4;
      f32x4 v = acc[mi][ni];
      if (z < 2) {
#pragma unroll
        for (int j = 0; j < 4; ++j) {
          int m = mb + j;
          int b = m >> 11, s = m & 2047;
          Cp[((size_t)((b * NHEAD + h) * S_LEN) + s) * HDIM + d] = f2bf(v[j] + bn);
        }
      } else {
        int b = mb >> 11, s = mb & 2047;
        s16x4 p;
#pragma unroll
        for (int j = 0; j < 4; ++j) p[j] = f2bf(v[j] + bn);
        *(s16x4*)&Cp[((size_t)((b * NHEAD + h) * HDIM) + d) * S_LEN + s] = p;
      }
    }
  }
}

// ---------------------------------------------------------------------------
// Output projection: tile 128x64, BK=64, grid 512 (32m x 16n), 48KB LDS ->
// 3 blocks/CU capacity, fully resident. bf16 A (attn out) @ Wto^T -> fp32.
// ---------------------------------------------------------------------------
__global__ __launch_bounds__(256, 2) void gemm_o_k(const short* __restrict__ A,
                                                   const short* __restrict__ Bt,
                                                   const float* __restrict__ bias,
                                                   float* __restrict__ C) {
  __shared__ short As[2 * 128 * 64];   // 32 KB
  __shared__ short Bs[2 * 64 * 64];    // 16 KB
  const int orig = blockIdx.x;                 // 512 = 64 per XCD
  const int wg = (orig & 7) * 64 + (orig >> 3);
  const int m0 = (wg >> 4) * 128;
  const int n0 = (wg & 15) * 64;

  const int tid = threadIdx.x;
  const int lane = tid & 63, w = tid >> 6;
  const int wm = w >> 1, wn = w & 1;
  const int lr = lane & 15, lg = lane >> 4;
  const int lr8 = lane >> 3;
  const int sl = lane & 7;
  const int scol = ((sl ^ lr8) << 3);

  f32x4 acc[4][2] = {};

  auto stage = [&](int buf, int k0) {
#pragma unroll
    for (int j = 0; j < 4; ++j) {
      const int rb = j * 4 + w;
      const int row = rb * 8 + lr8;
      gl_lds16(&A[(size_t)(m0 + row) * D_MODEL + k0 + scol],
               &As[buf * 8192 + rb * 512]);
    }
#pragma unroll
    for (int j = 0; j < 2; ++j) {
      const int rb = j * 4 + w;
      const int row = rb * 8 + lr8;
      gl_lds16(&Bt[(size_t)(n0 + row) * D_MODEL + k0 + scol],
               &Bs[buf * 4096 + rb * 512]);
    }
  };

  stage(0, 0);
  __syncthreads();

  for (int t = 0; t < D_MODEL / 64; ++t) {
    const int cur = t & 1;
    if (t + 1 < D_MODEL / 64) stage(cur ^ 1, (t + 1) * 64);
    const short* Ac = As + cur * 8192;
    const short* Bc = Bs + cur * 4096;
#pragma unroll
    for (int ks = 0; ks < 2; ++ks) {
      s16x8 af[4], bfr[2];
#pragma unroll
      for (int i = 0; i < 4; ++i) {
        const int Ra = wm * 64 + i * 16 + lr;
        af[i] = *(const s16x8*)&Ac[Ra * 64 + ((((ks << 2) | lg) ^ (Ra & 7)) << 3)];
      }
#pragma unroll
      for (int i = 0; i < 2; ++i) {
        const int Rb = wn * 32 + i * 16 + lr;
        bfr[i] = *(const s16x8*)&Bc[Rb * 64 + ((((ks << 2) | lg) ^ (Rb & 7)) << 3)];
      }
      __builtin_amdgcn_s_setprio(1);
#pragma unroll
      for (int mi = 0; mi < 4; ++mi)
#pragma unroll
        for (int ni = 0; ni < 2; ++ni)
          acc[mi][ni] = __builtin_amdgcn_mfma_f32_16x16x32_bf16(
              af[mi], bfr[ni], acc[mi][ni], 0, 0, 0);
      __builtin_amdgcn_s_setprio(0);
    }
    __syncthreads();
  }

#pragma unroll
  for (int ni = 0; ni < 2; ++ni) {
    const int n = n0 + wn * 32 + ni * 16 + lr;
    const float bn = bias[n];
#pragma unroll
    for (int mi = 0; mi < 4; ++mi) {
      const int mb = m0 + wm * 64 + mi * 16 + lg * 4;
      f32x4 v = acc[mi][ni];
#pragma unroll
      for (int j = 0; j < 4; ++j)
        C[(size_t)(mb + j) * D_MODEL + n] = v[j] + bn;
    }
  }
}

// ---------------------------------------------------------------------------
// One attention fragment step: QK^T (8 mfma) -> mask -> per-lane defer-max
// softmax -> pack -> PV (16 mfma). All state in VGPRs.
// ---------------------------------------------------------------------------
__device__ __forceinline__ void frag_step(const short* __restrict__ Kc,
                                          const short* __restrict__ Vc,
                                          int lr, int lg,
                                          const s16x8 qf0, const s16x8 qf1,
                                          int qrow, int kv0, bool domask,
                                          f32x4 (&o)[4], float& m_run,
                                          float& l_part) {
  f32x4 sc[4];
  __builtin_amdgcn_s_setprio(1);
#pragma unroll
  for (int g = 0; g < 4; ++g) {
    const int R = g * 16 + lr;
    const s16x8 kf0 = *(const s16x8*)&Kc[R * 64 + ((lg ^ (lr & 7)) << 3)];
    const s16x8 kf1 = *(const s16x8*)&Kc[R * 64 + (((4 | lg) ^ (lr & 7)) << 3)];
    f32x4 z = {0.f, 0.f, 0.f, 0.f};
    sc[g] = __builtin_amdgcn_mfma_f32_16x16x32_bf16(kf0, qf0, z, 0, 0, 0);
    sc[g] = __builtin_amdgcn_mfma_f32_16x16x32_bf16(kf1, qf1, sc[g], 0, 0, 0);
  }
  __builtin_amdgcn_s_setprio(0);

  if (domask) {  // block-uniform branch
#pragma unroll
    for (int g = 0; g < 4; ++g)
#pragma unroll
      for (int j = 0; j < 4; ++j)
        if (kv0 + g * 16 + lg * 4 + j > qrow) sc[g][j] = -1e30f;
  }

  float mg[4];
#pragma unroll
  for (int g = 0; g < 4; ++g)
    mg[g] = fmaxf(fmaxf(sc[g][0], sc[g][1]), fmaxf(sc[g][2], sc[g][3]));
  const float tm = fmaxf(fmaxf(mg[0], mg[1]), fmaxf(mg[2], mg[3]));

  if (!__all(tm <= m_run + 8.f)) {
    float tr = fmaxf(tm, m_run);
    tr = fmaxf(tr, __shfl_xor(tr, 16));
    tr = fmaxf(tr, __shfl_xor(tr, 32));
    const float corr = exp2f(m_run - tr);
    l_part *= corr;
#pragma unroll
    for (int dc = 0; dc < 4; ++dc) o[dc] = o[dc] * corr;
    m_run = tr;
  }

  s16x4 pf[4];
#pragma unroll
  for (int g = 0; g < 4; ++g) {
    const float e0 = exp2f(sc[g][0] - m_run);
    const float e1 = exp2f(sc[g][1] - m_run);
    const float e2 = exp2f(sc[g][2] - m_run);
    const float e3 = exp2f(sc[g][3] - m_run);
    pf[g] = pk4(e0, e1, e2, e3);
    l_part += (e0 + e1) + (e2 + e3);
  }

  __builtin_amdgcn_s_setprio(1);
#pragma unroll
  for (int g = 0; g < 4; ++g)
#pragma unroll
    for (int dc = 0; dc < 4; ++dc) {
      const int row = dc * 16 + lr;
      const s16x4 vf = *(const s16x4*)&Vc[row * 64 +
          (((2 * g + (lg >> 1)) ^ (lr & 7)) << 3) + ((lg & 1) << 2)];
      o[dc] = __builtin_amdgcn_mfma_f32_16x16x16bf16_1k(vf, pf[g], o[dc], 0, 0, 0);
    }
  __builtin_amdgcn_s_setprio(0);
}

// ---------------------------------------------------------------------------
// Flash attention (causal). grid 512, one 128-row q-block each, 4 waves.
// Each wave owns TWO 16-row fragments (rows r and r+64) -> each staged
// 64-key K/V tile serves 128 q-rows: staging bytes, barriers, and address
// VALU per key are HALVED vs round 6; MFMA per stage-round doubled.
// fragA skips the last kv-tile entirely (keys all causally masked).
// Pairing qt = (u&1) ? u>>1 : 15-(u>>1) makes consecutive (co-resident)
// blocks long+short complementary. XCD swizzle: 4 heads per XCD (K/V 2MB
// L2-resident).
// ---------------------------------------------------------------------------
__global__ __launch_bounds__(256, 3) void attn_k(const short* __restrict__ Q,
                                                 const short* __restrict__ K,
                                                 const short* __restrict__ Vt,
                                                 short* __restrict__ AO) {
  __shared__ short Ks[2][KVB * HDIM];
  __shared__ short Vs[2][HDIM * KVB];
  const int tid = threadIdx.x, w = tid >> 6, lane = tid & 63;
  const int lr = lane & 15, lg = lane >> 4;
  const int orig = blockIdx.x;                  // 512 = 64 per XCD
  const int wg = (orig & 7) * 64 + (orig >> 3);
  const int bh = wg >> 4;
  const int u = wg & 15;
  const int qt = (u & 1) ? (u >> 1) : 15 - (u >> 1);
  const int q0 = qt * 128, nt = 2 * qt + 2;
  const int b = bh >> 4, h = bh & 15;
  const size_t headQK = (size_t)bh * S_LEN * HDIM;
  const size_t headV = (size_t)bh * HDIM * S_LEN;
  const int rowA = q0 + w * 16 + lr;
  const int rowB = rowA + 64;

  const int l8 = lane >> 3, sl = lane & 7;
  const int scol = ((sl ^ l8) << 3);

  auto stage = [&](int kv0, int buf) {
#pragma unroll
    for (int j = 0; j < 2; ++j) {
      const int rb = w * 2 + j;
      const int row = rb * 8 + l8;
      gl_lds16(&K[headQK + (size_t)(kv0 + row) * HDIM + scol],
               &Ks[buf][rb * 512]);
      gl_lds16(&Vt[headV + (size_t)row * S_LEN + kv0 + scol],
               &Vs[buf][rb * 512]);
    }
  };

  const s16x8 qfA0 = *(const s16x8*)&Q[headQK + (size_t)rowA * HDIM + lg * 8];
  const s16x8 qfA1 = *(const s16x8*)&Q[headQK + (size_t)rowA * HDIM + 32 + lg * 8];
  const s16x8 qfB0 = *(const s16x8*)&Q[headQK + (size_t)rowB * HDIM + lg * 8];
  const s16x8 qfB1 = *(const s16x8*)&Q[headQK + (size_t)rowB * HDIM + 32 + lg * 8];

  f32x4 oA[4] = {}, oB[4] = {};
  float mA = -1e30f, mB = -1e30f, lA = 0.f, lB = 0.f;

  stage(0, 0);
  __syncthreads();

  for (int t = 0; t < nt; ++t) {
    if (t + 1 < nt) stage((t + 1) * KVB, (t + 1) & 1);
    const short* Kc = Ks[t & 1];
    const short* Vc = Vs[t & 1];
    const int kv0 = t * KVB;

    if (t < nt - 1)
      frag_step(Kc, Vc, lr, lg, qfA0, qfA1, rowA, kv0, t == nt - 2, oA, mA, lA);
    frag_step(Kc, Vc, lr, lg, qfB0, qfB1, rowB, kv0, t == nt - 1, oB, mB, lB);

    __syncthreads();
  }

  float ltA = lA, ltB = lB;
  ltA += __shfl_xor(ltA, 16); ltA += __shfl_xor(ltA, 32);
  ltB += __shfl_xor(ltB, 16); ltB += __shfl_xor(ltB, 32);
  const float invA = 1.f / ltA, invB = 1.f / ltB;
#pragma unroll
  for (int dc = 0; dc < 4; ++dc) {
    s16x4 pa, pb;
#pragma unroll
    for (int j = 0; j < 4; ++j) {
      pa[j] = f2bf(oA[dc][j] * invA);
      pb[j] = f2bf(oB[dc][j] * invB);
    }
    *(s16x4*)&AO[((size_t)(b * S_LEN + rowA)) * D_MODEL + h * HDIM + dc * 16 + lg * 4] = pa;
    *(s16x4*)&AO[((size_t)(b * S_LEN + rowB)) * D_MODEL + h * HDIM + dc * 16 + lg * 4] = pb;
  }
}

// ---------------------------------------------------------------------------
extern "C" void kernel_launch(void* const* d_in, const int* in_sizes, int n_in,
                              void* d_out, int out_size, void* d_ws, size_t ws_size,
                              hipStream_t stream) {
  const float* X  = (const float*)d_in[0];
  const float* Wq = (const float*)d_in[1];
  const float* bq = (const float*)d_in[2];
  const float* Wk = (const float*)d_in[3];
  const float* bk = (const float*)d_in[4];
  const float* Wv = (const float*)d_in[5];
  const float* bv = (const float*)d_in[6];
  const float* Wo = (const float*)d_in[7];
  const float* bo = (const float*)d_in[8];
  (void)in_sizes; (void)n_in; (void)out_size; (void)ws_size;

  char* ws = (char*)d_ws;
  const size_t WSZ = (size_t)D_MODEL * D_MODEL * sizeof(short);  // 2 MB
  const size_t QSZ = (size_t)M_TOT * D_MODEL * sizeof(short);    // 8 MB
  short* Wcat = (short*)ws;                       // 4 matrices, 8 MB
  short* Qb  = (short*)(ws + 4 * WSZ);
  short* Kb  = (short*)(ws + 4 * WSZ + QSZ);
  short* Vtb = (short*)(ws + 4 * WSZ + 2 * QSZ);
  short* AO  = (short*)(ws + 4 * WSZ + 3 * QSZ);  // doubles as Xb (bf16 X)
  short* Xb  = AO;  // X-cast consumed before attn writes AO
  short* Wto = Wcat + 3 * (size_t)D_MODEL * D_MODEL;

  xcast_k<<<dim3(M_TOT * D_MODEL / 2048), 256, 0, stream>>>(X, Xb);
  wtrans_k<<<dim3(32, 32, 4), dim3(32, 8), 0, stream>>>(Wq, Wk, Wv, Wo, Wcat);

  gemm_qkv_k<<<dim3(512), 256, 0, stream>>>(Xb, Wcat, bq, bk, bv,
                                            Qb, Kb, Vtb);

  attn_k<<<dim3(512), 256, 0, stream>>>(Qb, Kb, Vtb, AO);

  gemm_o_k<<<dim3(512), 256, 0, stream>>>(AO, Wto, bo, (float*)d_out);
}

// Round 8
// 105.311 us; speedup vs baseline: 1.3436x; 1.3436x over previous
//
#include <hip/hip_runtime.h>
#include <hip/hip_bf16.h>

#define S_LEN 2048
#define D_MODEL 1024
#define NHEAD 16
#define HDIM 64
#define BATCH 2
#define M_TOT (BATCH * S_LEN)   // 4096
#define KVB 64

typedef __attribute__((ext_vector_type(4))) float f32x4;
typedef __attribute__((ext_vector_type(4))) short s16x4;
typedef __attribute__((ext_vector_type(8))) short s16x8;

#define AS1 __attribute__((address_space(1)))
#define AS3 __attribute__((address_space(3)))

#define SC2 0.18033688011112042f  // (1/8) * log2(e)

__device__ inline short f2bf(float f) {
  unsigned u = __float_as_uint(f);
  return (short)((u + 0x7fffu + ((u >> 16) & 1u)) >> 16);
}

// HW packed f32->bf16 (RNE). No builtin on gfx950 -> inline asm (T12 recipe).
__device__ __forceinline__ unsigned cvtpk(float lo, float hi) {
  unsigned r;
  asm("v_cvt_pk_bf16_f32 %0, %1, %2" : "=v"(r) : "v"(lo), "v"(hi));
  return r;
}
__device__ __forceinline__ s16x4 pk4(float a, float b, float c, float d) {
  union { unsigned u[2]; s16x4 s; } x;
  x.u[0] = cvtpk(a, b);
  x.u[1] = cvtpk(c, d);
  return x.s;
}

__device__ __forceinline__ void gl_lds16(const short* g, short* l) {
  __builtin_amdgcn_global_load_lds((const AS1 void*)g, (AS3 void*)l, 16, 0, 0);
}

// ---------------------------------------------------------------------------
// X fp32 -> bf16 cast. grid 2048, block 256, 8 elems/thread.
// ---------------------------------------------------------------------------
__global__ __launch_bounds__(256) void xcast_k(const float* __restrict__ X,
                                               short* __restrict__ Xb) {
  const size_t i = ((size_t)blockIdx.x * 256 + threadIdx.x) * 8;
  float4 a = *(const float4*)&X[i];
  float4 b = *(const float4*)&X[i + 4];
  s16x8 p;
  p[0] = f2bf(a.x); p[1] = f2bf(a.y); p[2] = f2bf(a.z); p[3] = f2bf(a.w);
  p[4] = f2bf(b.x); p[5] = f2bf(b.y); p[6] = f2bf(b.z); p[7] = f2bf(b.w);
  *(s16x8*)&Xb[i] = p;
}

// ---------------------------------------------------------------------------
// Weight transpose + cast, all 4 weights into contiguous Wcat[z][n][k].
// Wq (z==0) pre-scaled by (1/8)*log2(e). grid (32,32,4), block (32,8)
// ---------------------------------------------------------------------------
__global__ __launch_bounds__(256) void wtrans_k(const float* __restrict__ W0,
                                                const float* __restrict__ W1,
                                                const float* __restrict__ W2,
                                                const float* __restrict__ W3,
                                                short* __restrict__ Wcat) {
  const int z = blockIdx.z;
  const float* W = z == 0 ? W0 : z == 1 ? W1 : z == 2 ? W2 : W3;
  short* Wt = Wcat + (size_t)z * D_MODEL * D_MODEL;
  const float scl = (z == 0) ? SC2 : 1.f;
  __shared__ float tile[32][33];
  const int tx = threadIdx.x, ty = threadIdx.y;
  const int n0 = blockIdx.x * 32, k0 = blockIdx.y * 32;
#pragma unroll
  for (int j = 0; j < 4; ++j)
    tile[ty + j * 8][tx] = W[(size_t)(k0 + ty + j * 8) * D_MODEL + n0 + tx];
  __syncthreads();
#pragma unroll
  for (int j = 0; j < 4; ++j)
    Wt[(size_t)(n0 + ty + j * 8) * D_MODEL + k0 + tx] =
        f2bf(tile[tx][ty + j * 8] * scl);
}

// ---------------------------------------------------------------------------
// Fused QKV projection: tile 128x192, BK=64, grid 512 (32m x 16n over
// N=3072), 2-phase double-buffered, 80KB LDS = exactly 2 blocks/CU.
// (unchanged from round 7 — measured improvement kept)
// ---------------------------------------------------------------------------
__global__ __launch_bounds__(256, 2) void gemm_qkv_k(
    const short* __restrict__ Xb, const short* __restrict__ Wcat,
    const float* __restrict__ bq, const float* __restrict__ bk,
    const float* __restrict__ bv, short* __restrict__ Qb,
    short* __restrict__ Kb, short* __restrict__ Vtb) {
  __shared__ short As[2 * 128 * 64];   // 32 KB
  __shared__ short Bs[2 * 192 * 64];   // 48 KB
  const int orig = blockIdx.x;                 // 512 = 64 per XCD
  const int wg = (orig & 7) * 64 + (orig >> 3);
  const int m0 = (wg >> 4) * 128;              // n-fastest within XCD chunk
  const int n0 = (wg & 15) * 192;

  const int tid = threadIdx.x;
  const int lane = tid & 63, w = tid >> 6;
  const int wm = w >> 1, wn = w & 1;
  const int lr = lane & 15, lg = lane >> 4;
  const int lr8 = lane >> 3;
  const int sl = lane & 7;
  const int scol = ((sl ^ lr8) << 3);

  f32x4 acc[4][6] = {};

  auto stage = [&](int buf, int k0) {
#pragma unroll
    for (int j = 0; j < 4; ++j) {
      const int rb = j * 4 + w;
      const int row = rb * 8 + lr8;
      gl_lds16(&Xb[(size_t)(m0 + row) * D_MODEL + k0 + scol],
               &As[buf * 8192 + rb * 512]);
    }
#pragma unroll
    for (int j = 0; j < 6; ++j) {
      const int rb = j * 4 + w;
      const int row = rb * 8 + lr8;
      gl_lds16(&Wcat[(size_t)(n0 + row) * D_MODEL + k0 + scol],
               &Bs[buf * 12288 + rb * 512]);
    }
  };

  stage(0, 0);
  __syncthreads();

  for (int t = 0; t < D_MODEL / 64; ++t) {
    const int cur = t & 1;
    if (t + 1 < D_MODEL / 64) stage(cur ^ 1, (t + 1) * 64);
    const short* Ac = As + cur * 8192;
    const short* Bc = Bs + cur * 12288;
#pragma unroll
    for (int ks = 0; ks < 2; ++ks) {
      s16x8 af[4], bfr[6];
#pragma unroll
      for (int i = 0; i < 4; ++i) {
        const int Ra = wm * 64 + i * 16 + lr;
        af[i] = *(const s16x8*)&Ac[Ra * 64 + ((((ks << 2) | lg) ^ (Ra & 7)) << 3)];
      }
#pragma unroll
      for (int i = 0; i < 6; ++i) {
        const int Rb = wn * 96 + i * 16 + lr;
        bfr[i] = *(const s16x8*)&Bc[Rb * 64 + ((((ks << 2) | lg) ^ (Rb & 7)) << 3)];
      }
      __builtin_amdgcn_s_setprio(1);
#pragma unroll
      for (int mi = 0; mi < 4; ++mi)
#pragma unroll
        for (int ni = 0; ni < 6; ++ni)
          acc[mi][ni] = __builtin_amdgcn_mfma_f32_16x16x32_bf16(
              af[mi], bfr[ni], acc[mi][ni], 0, 0, 0);
      __builtin_amdgcn_s_setprio(0);
    }
    __syncthreads();
  }

#pragma unroll
  for (int ni = 0; ni < 6; ++ni) {
    const int n = n0 + wn * 96 + ni * 16 + lr;
    const int z = n >> 10;              // uniform within a 16-chunk
    const float bn = (z == 0 ? bq[n & 1023] * SC2
                             : (z == 1 ? bk[n & 1023] : bv[n & 1023]));
    short* Cp = z == 0 ? Qb : z == 1 ? Kb : Vtb;
    const int h = (n >> 6) & 15, d = n & 63;
#pragma unroll
    for (int mi = 0; mi < 4; ++mi) {
      const int mb = m0 + wm * 64 + mi * 16 + lg * 4;
      f32x4 v = acc[mi][ni];
      if (z < 2) {
#pragma unroll
        for (int j = 0; j < 4; ++j) {
          int m = mb + j;
          int b = m >> 11, s = m & 2047;
          Cp[((size_t)((b * NHEAD + h) * S_LEN) + s) * HDIM + d] = f2bf(v[j] + bn);
        }
      } else {
        int b = mb >> 11, s = mb & 2047;
        s16x4 p;
#pragma unroll
        for (int j = 0; j < 4; ++j) p[j] = f2bf(v[j] + bn);
        *(s16x4*)&Cp[((size_t)((b * NHEAD + h) * HDIM) + d) * S_LEN + s] = p;
      }
    }
  }
}

// ---------------------------------------------------------------------------
// Output projection: tile 128x64, BK=64, grid 512. (unchanged from round 7)
// ---------------------------------------------------------------------------
__global__ __launch_bounds__(256, 2) void gemm_o_k(const short* __restrict__ A,
                                                   const short* __restrict__ Bt,
                                                   const float* __restrict__ bias,
                                                   float* __restrict__ C) {
  __shared__ short As[2 * 128 * 64];   // 32 KB
  __shared__ short Bs[2 * 64 * 64];    // 16 KB
  const int orig = blockIdx.x;                 // 512 = 64 per XCD
  const int wg = (orig & 7) * 64 + (orig >> 3);
  const int m0 = (wg >> 4) * 128;
  const int n0 = (wg & 15) * 64;

  const int tid = threadIdx.x;
  const int lane = tid & 63, w = tid >> 6;
  const int wm = w >> 1, wn = w & 1;
  const int lr = lane & 15, lg = lane >> 4;
  const int lr8 = lane >> 3;
  const int sl = lane & 7;
  const int scol = ((sl ^ lr8) << 3);

  f32x4 acc[4][2] = {};

  auto stage = [&](int buf, int k0) {
#pragma unroll
    for (int j = 0; j < 4; ++j) {
      const int rb = j * 4 + w;
      const int row = rb * 8 + lr8;
      gl_lds16(&A[(size_t)(m0 + row) * D_MODEL + k0 + scol],
               &As[buf * 8192 + rb * 512]);
    }
#pragma unroll
    for (int j = 0; j < 2; ++j) {
      const int rb = j * 4 + w;
      const int row = rb * 8 + lr8;
      gl_lds16(&Bt[(size_t)(n0 + row) * D_MODEL + k0 + scol],
               &Bs[buf * 4096 + rb * 512]);
    }
  };

  stage(0, 0);
  __syncthreads();

  for (int t = 0; t < D_MODEL / 64; ++t) {
    const int cur = t & 1;
    if (t + 1 < D_MODEL / 64) stage(cur ^ 1, (t + 1) * 64);
    const short* Ac = As + cur * 8192;
    const short* Bc = Bs + cur * 4096;
#pragma unroll
    for (int ks = 0; ks < 2; ++ks) {
      s16x8 af[4], bfr[2];
#pragma unroll
      for (int i = 0; i < 4; ++i) {
        const int Ra = wm * 64 + i * 16 + lr;
        af[i] = *(const s16x8*)&Ac[Ra * 64 + ((((ks << 2) | lg) ^ (Ra & 7)) << 3)];
      }
#pragma unroll
      for (int i = 0; i < 2; ++i) {
        const int Rb = wn * 32 + i * 16 + lr;
        bfr[i] = *(const s16x8*)&Bc[Rb * 64 + ((((ks << 2) | lg) ^ (Rb & 7)) << 3)];
      }
      __builtin_amdgcn_s_setprio(1);
#pragma unroll
      for (int mi = 0; mi < 4; ++mi)
#pragma unroll
        for (int ni = 0; ni < 2; ++ni)
          acc[mi][ni] = __builtin_amdgcn_mfma_f32_16x16x32_bf16(
              af[mi], bfr[ni], acc[mi][ni], 0, 0, 0);
      __builtin_amdgcn_s_setprio(0);
    }
    __syncthreads();
  }

#pragma unroll
  for (int ni = 0; ni < 2; ++ni) {
    const int n = n0 + wn * 32 + ni * 16 + lr;
    const float bn = bias[n];
#pragma unroll
    for (int mi = 0; mi < 4; ++mi) {
      const int mb = m0 + wm * 64 + mi * 16 + lg * 4;
      f32x4 v = acc[mi][ni];
#pragma unroll
      for (int j = 0; j < 4; ++j)
        C[(size_t)(mb + j) * D_MODEL + n] = v[j] + bn;
    }
  }
}

// ---------------------------------------------------------------------------
// Flash attention (causal) — round-6 structure restored (measured 57 µs):
// grid 1024, one 64-row q-tile per block, 4 waves, 4 blocks/CU.
// Round-8 additions:
//  - raw __builtin_amdgcn_exp2f (v_exp_f32, no ocml wrapper)
//  - diag tile: wave w computes only groups g <= w (g > w fully masked);
//    element mask needed only for g == w (uniform branches)
// ---------------------------------------------------------------------------
__global__ __launch_bounds__(256, 4) void attn_k(const short* __restrict__ Q,
                                                 const short* __restrict__ K,
                                                 const short* __restrict__ Vt,
                                                 short* __restrict__ AO) {
  __shared__ short Ks[2][KVB * HDIM];
  __shared__ short Vs[2][HDIM * KVB];
  const int tid = threadIdx.x, w = tid >> 6, lane = tid & 63;
  const int lr = lane & 15, lg = lane >> 4;
  const int orig = blockIdx.x;
  const int wg = (orig & 7) * 128 + (orig >> 3);
  const int bh = wg >> 5, qi = wg & 31;
  const int qt = (bh & 1) ? qi : 31 - qi;
  const int q0 = qt * 64, nt = qt + 1;
  const int b = bh >> 4, h = bh & 15;
  const size_t headQK = (size_t)bh * S_LEN * HDIM;
  const size_t headV = (size_t)bh * HDIM * S_LEN;
  const int qrow = q0 + w * 16 + lr;

  const int l8 = lane >> 3, sl = lane & 7;
  const int scol = ((sl ^ l8) << 3);

  auto stage = [&](int kv0, int buf) {
#pragma unroll
    for (int j = 0; j < 2; ++j) {
      const int rb = w * 2 + j;
      const int row = rb * 8 + l8;
      gl_lds16(&K[headQK + (size_t)(kv0 + row) * HDIM + scol],
               &Ks[buf][rb * 512]);
      gl_lds16(&Vt[headV + (size_t)row * S_LEN + kv0 + scol],
               &Vs[buf][rb * 512]);
    }
  };

  const s16x8 qf0 = *(const s16x8*)&Q[headQK + (size_t)qrow * HDIM + lg * 8];
  const s16x8 qf1 = *(const s16x8*)&Q[headQK + (size_t)qrow * HDIM + 32 + lg * 8];

  f32x4 o[4] = {};
  float m_run = -1e30f;
  float l_part = 0.f;   // per-lane partial; cross-lane reduced once at end

  stage(0, 0);
  __syncthreads();

  for (int t = 0; t < nt; ++t) {
    if (t + 1 < nt) stage((t + 1) * KVB, (t + 1) & 1);
    const short* Kc = Ks[t & 1];
    const short* Vc = Vs[t & 1];
    const bool diag = (t == nt - 1);
    const int gmax = diag ? (w + 1) : 4;   // wave-uniform

    // scores^T (already scaled to log2 domain): S^T = K @ Q'^T
    f32x4 sc[4];
    __builtin_amdgcn_s_setprio(1);
#pragma unroll
    for (int g = 0; g < 4; ++g) {
      if (g < gmax) {
        const int R = g * 16 + lr;
        const s16x8 kf0 = *(const s16x8*)&Kc[R * 64 + ((lg ^ (lr & 7)) << 3)];
        const s16x8 kf1 = *(const s16x8*)&Kc[R * 64 + (((4 | lg) ^ (lr & 7)) << 3)];
        f32x4 z = {0.f, 0.f, 0.f, 0.f};
        sc[g] = __builtin_amdgcn_mfma_f32_16x16x32_bf16(kf0, qf0, z, 0, 0, 0);
        sc[g] = __builtin_amdgcn_mfma_f32_16x16x32_bf16(kf1, qf1, sc[g], 0, 0, 0);
      }
    }
    __builtin_amdgcn_s_setprio(0);

    if (diag) {  // element mask only needed for the partial group g == w
#pragma unroll
      for (int g = 0; g < 4; ++g)
        if (g == w) {
#pragma unroll
          for (int j = 0; j < 4; ++j)
            if (lg * 4 + j > lr) sc[g][j] = -1e30f;
        }
    }

    // per-lane max over active groups
    float tm = -1e30f;
#pragma unroll
    for (int g = 0; g < 4; ++g)
      if (g < gmax)
        tm = fmaxf(tm, fmaxf(fmaxf(sc[g][0], sc[g][1]),
                             fmaxf(sc[g][2], sc[g][3])));

    // defer-max: full row-max reduce + rescale only when some row grew >THR=8
    if (!__all(tm <= m_run + 8.f)) {
      float tr = fmaxf(tm, m_run);
      tr = fmaxf(tr, __shfl_xor(tr, 16));
      tr = fmaxf(tr, __shfl_xor(tr, 32));
      const float corr = __builtin_amdgcn_exp2f(m_run - tr);
      l_part *= corr;
#pragma unroll
      for (int dc = 0; dc < 4; ++dc) o[dc] = o[dc] * corr;
      m_run = tr;
    }

    // P = exp2(sc - m_run), pack via HW cvt_pk, accumulate per-lane l
    s16x4 pf[4];
#pragma unroll
    for (int g = 0; g < 4; ++g) {
      if (g < gmax) {
        const float e0 = __builtin_amdgcn_exp2f(sc[g][0] - m_run);
        const float e1 = __builtin_amdgcn_exp2f(sc[g][1] - m_run);
        const float e2 = __builtin_amdgcn_exp2f(sc[g][2] - m_run);
        const float e3 = __builtin_amdgcn_exp2f(sc[g][3] - m_run);
        pf[g] = pk4(e0, e1, e2, e3);
        l_part += (e0 + e1) + (e2 + e3);
      }
    }

    __builtin_amdgcn_s_setprio(1);
#pragma unroll
    for (int g = 0; g < 4; ++g) {
      if (g < gmax) {
#pragma unroll
        for (int dc = 0; dc < 4; ++dc) {
          const int row = dc * 16 + lr;
          const s16x4 vf = *(const s16x4*)&Vc[row * 64 +
              (((2 * g + (lg >> 1)) ^ (lr & 7)) << 3) + ((lg & 1) << 2)];
          o[dc] = __builtin_amdgcn_mfma_f32_16x16x16bf16_1k(vf, pf[g], o[dc], 0, 0, 0);
        }
      }
    }
    __builtin_amdgcn_s_setprio(0);
    __syncthreads();
  }

  // single end-of-tile cross-lane reduce of the partial l (lanes of same row)
  float lt = l_part;
  lt += __shfl_xor(lt, 16);
  lt += __shfl_xor(lt, 32);
  const float inv = 1.f / lt;
#pragma unroll
  for (int dc = 0; dc < 4; ++dc) {
    s16x4 pk;
#pragma unroll
    for (int j = 0; j < 4; ++j) pk[j] = f2bf(o[dc][j] * inv);
    *(s16x4*)&AO[((size_t)(b * S_LEN + qrow)) * D_MODEL + h * HDIM + dc * 16 + lg * 4] = pk;
  }
}

// ---------------------------------------------------------------------------
extern "C" void kernel_launch(void* const* d_in, const int* in_sizes, int n_in,
                              void* d_out, int out_size, void* d_ws, size_t ws_size,
                              hipStream_t stream) {
  const float* X  = (const float*)d_in[0];
  const float* Wq = (const float*)d_in[1];
  const float* bq = (const float*)d_in[2];
  const float* Wk = (const float*)d_in[3];
  const float* bk = (const float*)d_in[4];
  const float* Wv = (const float*)d_in[5];
  const float* bv = (const float*)d_in[6];
  const float* Wo = (const float*)d_in[7];
  const float* bo = (const float*)d_in[8];
  (void)in_sizes; (void)n_in; (void)out_size; (void)ws_size;

  char* ws = (char*)d_ws;
  const size_t WSZ = (size_t)D_MODEL * D_MODEL * sizeof(short);  // 2 MB
  const size_t QSZ = (size_t)M_TOT * D_MODEL * sizeof(short);    // 8 MB
  short* Wcat = (short*)ws;                       // 4 matrices, 8 MB
  short* Qb  = (short*)(ws + 4 * WSZ);
  short* Kb  = (short*)(ws + 4 * WSZ + QSZ);
  short* Vtb = (short*)(ws + 4 * WSZ + 2 * QSZ);
  short* AO  = (short*)(ws + 4 * WSZ + 3 * QSZ);  // doubles as Xb (bf16 X)
  short* Xb  = AO;  // X-cast consumed before attn writes AO
  short* Wto = Wcat + 3 * (size_t)D_MODEL * D_MODEL;

  xcast_k<<<dim3(M_TOT * D_MODEL / 2048), 256, 0, stream>>>(X, Xb);
  wtrans_k<<<dim3(32, 32, 4), dim3(32, 8), 0, stream>>>(Wq, Wk, Wv, Wo, Wcat);

  gemm_qkv_k<<<dim3(512), 256, 0, stream>>>(Xb, Wcat, bq, bk, bv,
                                            Qb, Kb, Vtb);

  attn_k<<<dim3(1024), 256, 0, stream>>>(Qb, Kb, Vtb, AO);

  gemm_o_k<<<dim3(512), 256, 0, stream>>>(AO, Wto, bo, (float*)d_out);
}